// Round 1
// baseline (612.785 us; speedup 1.0000x reference)
//
#include <hip/hip_runtime.h>

#define B 8
#define NF 4096
#define NT 4096
#define D_HID 128
#define D_OUT 32
#define D_V 16

__device__ inline float fast_exp2(float x) {
#if __has_builtin(__builtin_amdgcn_exp2f)
  return __builtin_amdgcn_exp2f(x);
#else
  return exp2f(x);
#endif
}

// ---------------- MLP: [N,3] -> relu(x W1 + b1) W2 + b2 -> [N,32] ----------------
__global__ __launch_bounds__(256) void mlp_kernel(
    const float* __restrict__ x, const float* __restrict__ W1,
    const float* __restrict__ b1, const float* __restrict__ W2,
    const float* __restrict__ b2, float* __restrict__ out) {
  const int t = blockIdx.x * 256 + threadIdx.x;
  const float x0 = x[t * 3 + 0];
  const float x1 = x[t * 3 + 1];
  const float x2 = x[t * 3 + 2];
  float acc[D_OUT];
#pragma unroll
  for (int o = 0; o < D_OUT; ++o) acc[o] = b2[o];
#pragma unroll 4
  for (int h = 0; h < D_HID; ++h) {
    // weights are wave-uniform -> scalar loads
    float hv = fmaf(x2, W1[2 * D_HID + h],
               fmaf(x1, W1[1 * D_HID + h],
               fmaf(x0, W1[0 * D_HID + h], b1[h])));
    hv = fmaxf(hv, 0.0f);
#pragma unroll
    for (int o = 0; o < D_OUT; ++o) acc[o] = fmaf(hv, W2[h * D_OUT + o], acc[o]);
  }
  float* op = out + (size_t)t * D_OUT;
#pragma unroll
  for (int o = 0; o < D_OUT; ++o) op[o] = acc[o];
}

// ------------- fused L1-dist + softmax(over i) + PV, flash style over NF -------------
// thread = one j column; wave-uniform Wk/values rows; partials per NF-chunk.
__global__ __launch_bounds__(256) void attn_kernel(
    const float* __restrict__ Wk, const float* __restrict__ Wq,
    const float* __restrict__ Vf, float* __restrict__ partial,
    int nchunks, int chlen) {
  const int j = blockIdx.x * 256 + threadIdx.x;
  const int b = blockIdx.y;
  const int c = blockIdx.z;
  const int i0 = c * chlen;

  // load q row (once)
  const float* qp = Wq + ((size_t)b * NT + j) * D_OUT;
  float q[D_OUT];
#pragma unroll
  for (int d = 0; d < D_OUT; d += 4) {
    float4 t4 = *reinterpret_cast<const float4*>(qp + d);
    q[d + 0] = t4.x; q[d + 1] = t4.y; q[d + 2] = t4.z; q[d + 3] = t4.w;
  }

  constexpr float C2 = -0.72134752044448170368f;  // -log2(e)/2

  float m = -1e30f;  // running max in log2 domain; first iter self-normalizes
  float l = 0.0f;
  float acc[D_V];
#pragma unroll
  for (int k = 0; k < D_V; ++k) acc[k] = 0.0f;

  const float* kr = Wk + ((size_t)b * NF + i0) * D_OUT;
  const float* vr = Vf + ((size_t)b * NF + i0) * D_V;

  for (int i = 0; i < chlen; ++i) {
    const float4 k0 = *reinterpret_cast<const float4*>(kr + 0);
    const float4 k1 = *reinterpret_cast<const float4*>(kr + 4);
    const float4 k2 = *reinterpret_cast<const float4*>(kr + 8);
    const float4 k3 = *reinterpret_cast<const float4*>(kr + 12);
    const float4 k4 = *reinterpret_cast<const float4*>(kr + 16);
    const float4 k5 = *reinterpret_cast<const float4*>(kr + 20);
    const float4 k6 = *reinterpret_cast<const float4*>(kr + 24);
    const float4 k7 = *reinterpret_cast<const float4*>(kr + 28);

    // 4 independent accumulation chains, 2 VALU/dim (v_sub + v_add|abs|)
    float a0 = fabsf(k0.x - q[0]);
    float a1 = fabsf(k0.y - q[1]);
    float a2 = fabsf(k0.z - q[2]);
    float a3 = fabsf(k0.w - q[3]);
    a0 += fabsf(k1.x - q[4]);
    a1 += fabsf(k1.y - q[5]);
    a2 += fabsf(k1.z - q[6]);
    a3 += fabsf(k1.w - q[7]);
    a0 += fabsf(k2.x - q[8]);
    a1 += fabsf(k2.y - q[9]);
    a2 += fabsf(k2.z - q[10]);
    a3 += fabsf(k2.w - q[11]);
    a0 += fabsf(k3.x - q[12]);
    a1 += fabsf(k3.y - q[13]);
    a2 += fabsf(k3.z - q[14]);
    a3 += fabsf(k3.w - q[15]);
    a0 += fabsf(k4.x - q[16]);
    a1 += fabsf(k4.y - q[17]);
    a2 += fabsf(k4.z - q[18]);
    a3 += fabsf(k4.w - q[19]);
    a0 += fabsf(k5.x - q[20]);
    a1 += fabsf(k5.y - q[21]);
    a2 += fabsf(k5.z - q[22]);
    a3 += fabsf(k5.w - q[23]);
    a0 += fabsf(k6.x - q[24]);
    a1 += fabsf(k6.y - q[25]);
    a2 += fabsf(k6.z - q[26]);
    a3 += fabsf(k6.w - q[27]);
    a0 += fabsf(k7.x - q[28]);
    a1 += fabsf(k7.y - q[29]);
    a2 += fabsf(k7.z - q[30]);
    a3 += fabsf(k7.w - q[31]);
    const float dist = (a0 + a1) + (a2 + a3);

    const float d2 = dist * dist;
    float parg = fmaf(C2, d2, -m);  // s2 - m
    if (__any(parg > 4.0f)) {       // rare, wave-uniform rescale
      const float s2 = C2 * d2;
      const float mn = fmaxf(m, s2);
      const float al = fast_exp2(m - mn);
      l *= al;
#pragma unroll
      for (int k = 0; k < D_V; ++k) acc[k] *= al;
      m = mn;
      parg = s2 - m;
    }
    const float p = fast_exp2(parg);

    const float4 v0 = *reinterpret_cast<const float4*>(vr + 0);
    const float4 v1 = *reinterpret_cast<const float4*>(vr + 4);
    const float4 v2 = *reinterpret_cast<const float4*>(vr + 8);
    const float4 v3 = *reinterpret_cast<const float4*>(vr + 12);

    l += p;
    acc[0]  = fmaf(p, v0.x, acc[0]);
    acc[1]  = fmaf(p, v0.y, acc[1]);
    acc[2]  = fmaf(p, v0.z, acc[2]);
    acc[3]  = fmaf(p, v0.w, acc[3]);
    acc[4]  = fmaf(p, v1.x, acc[4]);
    acc[5]  = fmaf(p, v1.y, acc[5]);
    acc[6]  = fmaf(p, v1.z, acc[6]);
    acc[7]  = fmaf(p, v1.w, acc[7]);
    acc[8]  = fmaf(p, v2.x, acc[8]);
    acc[9]  = fmaf(p, v2.y, acc[9]);
    acc[10] = fmaf(p, v2.z, acc[10]);
    acc[11] = fmaf(p, v2.w, acc[11]);
    acc[12] = fmaf(p, v3.x, acc[12]);
    acc[13] = fmaf(p, v3.y, acc[13]);
    acc[14] = fmaf(p, v3.z, acc[14]);
    acc[15] = fmaf(p, v3.w, acc[15]);

    kr += D_OUT;
    vr += D_V;
  }

  float* ps = partial + ((size_t)((b * NT + j) * nchunks + c)) * 18;
  ps[0] = m;
  ps[1] = l;
#pragma unroll
  for (int k = 0; k < D_V; ++k) ps[2 + k] = acc[k];
}

// ---------------- combine NF-chunk partials -> output ----------------
__global__ __launch_bounds__(256) void combine_kernel(
    const float* __restrict__ partial, float* __restrict__ out, int nchunks) {
  const int t = blockIdx.x * 256 + threadIdx.x;  // = b*NT + j
  const float* ps = partial + (size_t)t * nchunks * 18;
  float M = -1e30f;
  for (int c = 0; c < nchunks; ++c) M = fmaxf(M, ps[c * 18]);
  float L = 0.0f;
  float acc[D_V];
#pragma unroll
  for (int k = 0; k < D_V; ++k) acc[k] = 0.0f;
  for (int c = 0; c < nchunks; ++c) {
    const float w = fast_exp2(ps[c * 18] - M);
    L = fmaf(w, ps[c * 18 + 1], L);
#pragma unroll
    for (int k = 0; k < D_V; ++k) acc[k] = fmaf(w, ps[c * 18 + 2 + k], acc[k]);
  }
  const float inv = 1.0f / L;
  float* op = out + (size_t)t * D_V;
#pragma unroll
  for (int k = 0; k < D_V; ++k) op[k] = acc[k] * inv;
}

extern "C" void kernel_launch(void* const* d_in, const int* in_sizes, int n_in,
                              void* d_out, int out_size, void* d_ws, size_t ws_size,
                              hipStream_t stream) {
  const float* coords_f = (const float*)d_in[0];
  const float* values_f = (const float*)d_in[1];
  const float* coords_t = (const float*)d_in[2];
  const float* Wk1 = (const float*)d_in[3];
  const float* bk1 = (const float*)d_in[4];
  const float* Wk2 = (const float*)d_in[5];
  const float* bk2 = (const float*)d_in[6];
  const float* Wq1 = (const float*)d_in[7];
  const float* bq1 = (const float*)d_in[8];
  const float* Wq2 = (const float*)d_in[9];
  const float* bq2 = (const float*)d_in[10];
  float* out = (float*)d_out;

  float* Wk = (float*)d_ws;                        // 4 MB
  float* Wq = Wk + (size_t)B * NF * D_OUT;         // 4 MB
  float* partial = Wq + (size_t)B * NT * D_OUT;

  const size_t fixed = (size_t)(B * NF * D_OUT + B * NT * D_OUT) * sizeof(float);
  int nchunks = 8;
  while (nchunks > 1 &&
         fixed + (size_t)B * NT * nchunks * 18 * sizeof(float) > ws_size)
    nchunks >>= 1;
  const int chlen = NF / nchunks;

  hipLaunchKernelGGL(mlp_kernel, dim3(B * NF / 256), dim3(256), 0, stream,
                     coords_f, Wk1, bk1, Wk2, bk2, Wk);
  hipLaunchKernelGGL(mlp_kernel, dim3(B * NT / 256), dim3(256), 0, stream,
                     coords_t, Wq1, bq1, Wq2, bq2, Wq);
  hipLaunchKernelGGL(attn_kernel, dim3(NT / 256, B, nchunks), dim3(256), 0, stream,
                     Wk, Wq, values_f, partial, nchunks, chlen);
  hipLaunchKernelGGL(combine_kernel, dim3(B * NT / 256), dim3(256), 0, stream,
                     partial, out, nchunks);
}